// Round 12
// baseline (6626.267 us; speedup 1.0000x reference)
//
#include <hip/hip_runtime.h>
#include <math.h>

#define NB 16
#define NC 512
#define NH 38
#define NW 50
#define NHW 1900          // 38*50
#define NPOS 30400        // 16*1900
#define NANCH 17100       // 1900*9
#define PRE_N 6000
#define POST_N 300
#define KTOT 4608         // 512*9
#define NIT 576           // KTOT/8
#define IMGH 608.0f
#define IMGW 800.0f

// ---------------------------------------------------------------------------
// Kernel 1: 3x3 conv (pad 1) + bias + ReLU, implicit GEMM, f64 VALU.
// v5: BARRIER-FREE. Each of the 4 waves owns a 32co x 64pos sub-tile with a
// PRIVATE double-buffered LDS region (A-slices disjoint; B im2col replicated
// per wave -- L1/L2-cached). No __syncthreads in the K-loop: waves pipeline
// independently; same-wave lgkmcnt/vmcnt ordering is compiler-inserted.
// Per-accumulator k-order serial 0..4607 with identical fused-FMA expressions
// -> bitwise identical to the verified r4/r9/r10/r11 activations.
// Grid (30 pos-tiles, 4 co-tiles, 16 b), block 256 (4 waves).
// ---------------------------------------------------------------------------
__global__ __launch_bounds__(256)
void conv_f64_v5(const float* __restrict__ x, const float* __restrict__ w,
                 const float* __restrict__ bias, float* __restrict__ out)
{
    const int b    = blockIdx.z;
    const int co0  = blockIdx.y * 128;
    const int pos0 = blockIdx.x * 64;

    // per-wave private buffers: Ad[wave][buf][k][co(32,pad34)], Bd[wave][buf][k][slot]
    __shared__ __align__(16) double Ad[4][2][8][34];   // 17408 B
    __shared__ __align__(16) double Bd[4][2][8][66];   // 33792 B

    const int tid  = threadIdx.x;
    const int wv   = tid >> 6;
    const int lane = tid & 63;
    const int tyw  = lane >> 4;   // 0..3: co sub-group (8 consecutive co)
    const int tx   = lane & 15;   // 0..15: pos group (4 consecutive pos)

    double acc[8][4];
#pragma unroll
    for (int m = 0; m < 8; ++m)
#pragma unroll
        for (int n = 0; n < 4; ++n) acc[m][n] = 0.0;

    const float* xb = x + (size_t)b * NC * NHW;

    // ---- A staging (per wave): lane -> (coiA = lane>>1 in [0,32), k4A), float4
    const int coiA = lane >> 1;
    const int k4A  = (lane & 1) * 4;
    const float* wptr = w + (size_t)(co0 + wv * 32 + coiA) * KTOT + k4A;

    // ---- B staging (per wave): lane owns position pi = lane, all 8 kk
    const int slotB = ((lane & 3) << 4) + (lane >> 2);   // v4's interleave
    const int pB    = pos0 + lane;
    const bool okp  = pB < NHW;
    const int pyB   = pB / NW;
    const int pxB   = pB - pyB * NW;

    // incremental im2col state for kk=0 (k0 = it*8): k=0 -> ci=0, ky=0, kx=0
    int ky0 = 0, kx0 = 0;
    const float* xci0 = xb;

    float4 wa;
    float  bs[8];

    // load B tile for current state (walk kk=0..7 from (ky0,kx0))
#define LOAD_B()                                                              \
    {                                                                         \
        int ky = ky0, kx = kx0;                                               \
        const float* xc = xci0;                                               \
        _Pragma("unroll")                                                     \
        for (int j = 0; j < 8; ++j) {                                         \
            const int yy = pyB + ky - 1;                                      \
            const int xx = pxB + kx - 1;                                      \
            bs[j] = (okp && (unsigned)yy < (unsigned)NH &&                    \
                     (unsigned)xx < (unsigned)NW) ? xc[yy * NW + xx] : 0.f;   \
            ++kx;                                                             \
            if (kx == 3) { kx = 0; ++ky; if (ky == 3) { ky = 0; xc += NHW; } }\
        }                                                                     \
    }

    // advance kk=0 state by k += 8  <=>  rr -= 1 (mod 9) with ci carry
#define ADV_STATE()                                                           \
    {                                                                         \
        const bool wrap = (ky0 == 0) && (kx0 == 0);                           \
        if (wrap) { ky0 = 2; kx0 = 2; }                                       \
        else {                                                                \
            --kx0;                                                            \
            if (kx0 < 0) { kx0 = 2; --ky0; }                                  \
            xci0 += NHW;                                                      \
        }                                                                     \
    }

#define STAGE(buf)                                                            \
    {                                                                         \
        Ad[wv][buf][k4A + 0][coiA] = (double)wa.x;                            \
        Ad[wv][buf][k4A + 1][coiA] = (double)wa.y;                            \
        Ad[wv][buf][k4A + 2][coiA] = (double)wa.z;                            \
        Ad[wv][buf][k4A + 3][coiA] = (double)wa.w;                            \
        _Pragma("unroll")                                                     \
        for (int j = 0; j < 8; ++j) Bd[wv][buf][j][slotB] = (double)bs[j];    \
    }

    // ---- prologue: tile 0 into buf 0 (no barrier: wave-private) ----
    wa = *reinterpret_cast<const float4*>(wptr);
    LOAD_B();
    ADV_STATE();
    STAGE(0);

    int cur = 0;
    for (int it = 0; it < NIT; ++it) {
        const bool more = (it + 1) < NIT;
        // ---- issue next tile's global loads (overlap with FMA below) ----
        if (more) {
            wptr += 8;
            wa = *reinterpret_cast<const float4*>(wptr);
            LOAD_B();
            ADV_STATE();
        }

        // ---- FMA block on buf[cur] ----
#pragma unroll
        for (int kk = 0; kk < 8; ++kk) {
            double av[8], bv[4];
#pragma unroll
            for (int m = 0; m < 8; ++m) av[m] = Ad[wv][cur][kk][tyw * 8 + m];
#pragma unroll
            for (int n = 0; n < 4; ++n) bv[n] = Bd[wv][cur][kk][n * 16 + tx];
#pragma unroll
            for (int m = 0; m < 8; ++m)
#pragma unroll
                for (int n = 0; n < 4; ++n) acc[m][n] += av[m] * bv[n];
        }

        // ---- stage next tile into the other buffer (wave-private, no barrier)
        if (more) {
            const int nb = cur ^ 1;
            STAGE(nb);
        }
        cur ^= 1;
    }
#undef LOAD_B
#undef ADV_STATE
#undef STAGE

    // ---- epilogue: thread owns co = co0+wv*32+tyw*8+m, pos = pos0+tx*4..+3
    const int pos = pos0 + tx * 4;
#pragma unroll
    for (int m = 0; m < 8; ++m) {
        const int co = co0 + wv * 32 + tyw * 8 + m;
        const double bi = (double)bias[co];
        if (pos < NHW) {   // NHW%4==0: float4 never straddles the edge
            float* orow = out + ((size_t)b * NC + co) * NHW;
            float4 v;
            double d0 = acc[m][0] + bi;
            double d1 = acc[m][1] + bi;
            double d2 = acc[m][2] + bi;
            double d3 = acc[m][3] + bi;
            v.x = (float)(d0 > 0.0 ? d0 : 0.0);
            v.y = (float)(d1 > 0.0 ? d1 : 0.0);
            v.z = (float)(d2 > 0.0 ? d2 : 0.0);
            v.w = (float)(d3 > 0.0 ? d3 : 0.0);
            *reinterpret_cast<float4*>(&orow[pos]) = v;
        }
    }
}

// ---------------------------------------------------------------------------
// Kernel 2: head (18 cls + 36 reg 1x1) with FP64 accumulation (verified r4,
// byte-identical).
// ---------------------------------------------------------------------------
__global__ __launch_bounds__(256)
void head_f64(const float* __restrict__ act,
              const float* __restrict__ cls_w, const float* __restrict__ cls_b,
              const float* __restrict__ reg_w, const float* __restrict__ reg_b,
              float* __restrict__ boxes, float* __restrict__ scores)
{
    const int p = blockIdx.x * 256 + threadIdx.x;
    if (p >= NPOS) return;
    const int b  = p / NHW;
    const int hw = p - b * NHW;

    const float* av = act + (size_t)b * NC * NHW + hw;

    double acc[54];
#pragma unroll
    for (int o = 0; o < 54; ++o) acc[o] = 0.0;

    for (int c = 0; c < NC; ++c) {
        const double v = (double)av[(size_t)c * NHW];
#pragma unroll
        for (int o = 0; o < 18; ++o) acc[o]      += v * (double)cls_w[o * NC + c];
#pragma unroll
        for (int o = 0; o < 36; ++o) acc[18 + o] += v * (double)reg_w[o * NC + c];
    }

    float lg[18];
#pragma unroll
    for (int o = 0; o < 18; ++o) lg[o] = (float)(acc[o] + (double)cls_b[o]);
    float loc[36];
#pragma unroll
    for (int o = 0; o < 36; ++o) loc[o] = (float)(acc[18 + o] + (double)reg_b[o]);

    double mx = -1e300;
#pragma unroll
    for (int o = 0; o < 18; ++o) mx = fmax(mx, (double)lg[o]);
    double sum = 0.0;
#pragma unroll
    for (int o = 0; o < 18; ++o) sum += exp((double)lg[o] - mx);
    const double inv = 1.0 / sum;

    const int hy = hw / NW;
    const int hx = hw - hy * NW;
    const float shy = (float)(hy * 16);
    const float shx = (float)(hx * 16);

    const double rats[3] = {0.5, 1.0, 2.0};
    const double scls[3] = {8.0, 16.0, 32.0};

#pragma unroll
    for (int a = 0; a < 9; ++a) {
        const int ir = a / 3, is = a - ir * 3;
        const double hh = 16.0 * scls[is] * sqrt(rats[ir]);
        const double wd = 16.0 * scls[is] * sqrt(1.0 / rats[ir]);
        const float ay1 = (float)(8.0 - hh * 0.5) + shy;
        const float ax1 = (float)(8.0 - wd * 0.5) + shx;
        const float ay2 = (float)(8.0 + hh * 0.5) + shy;
        const float ax2 = (float)(8.0 + wd * 0.5) + shx;
        const float ahf = ay2 - ay1;
        const float awf = ax2 - ax1;
        const float acy = ay1 + 0.5f * ahf;
        const float acx = ax1 + 0.5f * awf;

        const double ah = (double)ahf, aw = (double)awf;
        const double dy = (double)loc[4 * a + 0];
        const double dx = (double)loc[4 * a + 1];
        const double dh = (double)loc[4 * a + 2];
        const double dw = (double)loc[4 * a + 3];
        const double cy = dy * ah + (double)acy;
        const double cx = dx * aw + (double)acx;
        const double bh = exp(dh) * ah;
        const double bw = exp(dw) * aw;
        float y1 = (float)(cy - 0.5 * bh);
        float x1 = (float)(cx - 0.5 * bw);
        float y2 = (float)(cy + 0.5 * bh);
        float x2 = (float)(cx + 0.5 * bw);
        y1 = fminf(fmaxf(y1, 0.f), IMGH);
        y2 = fminf(fmaxf(y2, 0.f), IMGH);
        x1 = fminf(fmaxf(x1, 0.f), IMGW);
        x2 = fminf(fmaxf(x2, 0.f), IMGW);
        const bool keep = ((y2 - y1) >= 16.0f) && ((x2 - x1) >= 16.0f);

        float sc = (float)(exp((double)lg[2 * a + 1] - mx) * inv);
        if (!keep) sc = -INFINITY;

        const int n = hw * 9 + a;
        float4 bx; bx.x = y1; bx.y = x1; bx.z = y2; bx.w = x2;
        *reinterpret_cast<float4*>(&boxes[((size_t)b * NANCH + n) * 4]) = bx;
        scores[(size_t)b * NANCH + n] = sc;
    }
}

// ---------------------------------------------------------------------------
// Kernel 3: exact rank sort (verified r4, byte-identical).
// ---------------------------------------------------------------------------
__global__ __launch_bounds__(256)
void rank2(const float* __restrict__ scores, const float* __restrict__ boxes,
           float* __restrict__ sortedS, float* __restrict__ sortedB)
{
    const int b = blockIdx.y;
    const int i = blockIdx.x * 256 + threadIdx.x;
    if (i >= NANCH) return;
    const float si = scores[(size_t)b * NANCH + i];
    const float* sb = scores + (size_t)b * NANCH;
    int rank = 0;
    for (int j = 0; j < NANCH; ++j) {
        const float sj = sb[j];
        rank += (sj > si) || (sj == si && j < i);
    }
    if (rank < PRE_N) {
        sortedS[(size_t)b * PRE_N + rank] = si;
        const float4 bx = *reinterpret_cast<const float4*>(&boxes[((size_t)b * NANCH + i) * 4]);
        *reinterpret_cast<float4*>(&sortedB[((size_t)b * PRE_N + rank) * 4]) = bx;
    }
}

// ---------------------------------------------------------------------------
// Kernel 4: greedy NMS, kept-list formulation. PROVEN bitwise-identical to
// the reference-literal nms2 on this workload (r7+r8 shadow probes).
// ---------------------------------------------------------------------------
__global__ __launch_bounds__(64)
void nms3(const float* __restrict__ sortedS, const float* __restrict__ sortedB,
          float* __restrict__ out)
{
    const int b    = blockIdx.x;
    const int lane = threadIdx.x;

    __shared__ float ky1[POST_N], kx1[POST_N], ky2[POST_N], kx2[POST_N];
    __shared__ float kar[POST_N], ksc[POST_N];
    __shared__ float cs[256];
    __shared__ float cb[256][4];

    const float* SS = sortedS + (size_t)b * PRE_N;
    const float* BB = sortedB + (size_t)b * PRE_N * 4;

    int nk = 0;
    bool done = false;
    for (int c0 = 0; c0 < PRE_N && !done; c0 += 256) {
        __syncthreads();
        for (int i = lane; i < 256; i += 64) {
            const int gi = c0 + i;
            if (gi < PRE_N) {
                cs[i] = SS[gi];
                const float4 bx = *reinterpret_cast<const float4*>(&BB[(size_t)gi * 4]);
                cb[i][0] = bx.x; cb[i][1] = bx.y; cb[i][2] = bx.z; cb[i][3] = bx.w;
            } else {
                cs[i] = -INFINITY;
                cb[i][0] = 0.f; cb[i][1] = 0.f; cb[i][2] = 0.f; cb[i][3] = 0.f;
            }
        }
        __syncthreads();

        for (int ic = 0; ic < 256; ++ic) {
            const float sc = cs[ic];
            if (sc == -INFINITY) { done = true; break; }
            const float y1 = cb[ic][0], x1 = cb[ic][1];
            const float y2 = cb[ic][2], x2 = cb[ic][3];
            const float areaC = fmaxf(y2 - y1, 0.f) * fmaxf(x2 - x1, 0.f);
            bool sup = false;
            for (int t = lane; t < nk; t += 64) {
                const float yy1 = fmaxf(y1, ky1[t]);
                const float xx1 = fmaxf(x1, kx1[t]);
                const float yy2 = fminf(y2, ky2[t]);
                const float xx2 = fminf(x2, kx2[t]);
                const float inter = fmaxf(yy2 - yy1, 0.f) * fmaxf(xx2 - xx1, 0.f);
                const float iou = inter / (areaC + kar[t] - inter + 1e-9f);
                if (iou > 0.7f) sup = true;
            }
            if (__ballot(sup) == 0ull) {
                if (lane == 0) {
                    ky1[nk] = y1; kx1[nk] = x1; ky2[nk] = y2; kx2[nk] = x2;
                    kar[nk] = areaC; ksc[nk] = sc;
                }
                __syncthreads();
                ++nk;
                if (nk == POST_N) { done = true; break; }
            }
        }
    }

    __syncthreads();
    for (int k2 = lane; k2 < POST_N; k2 += 64) {
        float o0 = 0.f, o1 = 0.f, o2 = 0.f, o3 = 0.f, o4 = 0.f;
        if (k2 < nk) {
            o0 = ky1[k2]; o1 = kx1[k2]; o2 = ky2[k2]; o3 = kx2[k2]; o4 = ksc[k2];
        }
        float* orow = out + ((size_t)b * POST_N + k2) * 5;
        orow[0] = o0; orow[1] = o1; orow[2] = o2; orow[3] = o3; orow[4] = o4;
    }
}

// ---------------------------------------------------------------------------
static const float* pick_input(void* const* d_in, const int* in_sizes, int n_in,
                               int want, int fallback)
{
    for (int i = 0; i < n_in; ++i)
        if (in_sizes[i] == want) return (const float*)d_in[i];
    return (const float*)d_in[fallback];
}

extern "C" void kernel_launch(void* const* d_in, const int* in_sizes, int n_in,
                              void* d_out, int out_size, void* d_ws, size_t ws_size,
                              hipStream_t stream)
{
    const float* x       = pick_input(d_in, in_sizes, n_in, 15564800, 0);
    const float* share_w = pick_input(d_in, in_sizes, n_in, 2359296, 1);
    const float* share_b = pick_input(d_in, in_sizes, n_in, 512, 2);
    const float* cls_w   = pick_input(d_in, in_sizes, n_in, 9216, 3);
    const float* cls_b   = pick_input(d_in, in_sizes, n_in, 18, 4);
    const float* reg_w   = pick_input(d_in, in_sizes, n_in, 18432, 5);
    const float* reg_b   = pick_input(d_in, in_sizes, n_in, 36, 6);
    float* out = (float*)d_out;

    // workspace layout (floats); total 17,412,800 = 69.7 MB (fits, r3-r11)
    float* W = (float*)d_ws;
    float* act     = W;                   // 16*512*1900 = 15,564,800
    float* boxes   = W + 15564800;        // 16*17100*4 =  1,094,400
    float* scores  = W + 16659200;        // 16*17100   =    273,600
    float* sortedB = W + 16932800;        // 16*6000*4  =    384,000
    float* sortedS = W + 17316800;        // 16*6000    =     96,000

    conv_f64_v5<<<dim3(30, 4, NB), 256, 0, stream>>>(x, share_w, share_b, act);

    head_f64<<<dim3(119), 256, 0, stream>>>(act, cls_w, cls_b, reg_w, reg_b,
                                            boxes, scores);

    rank2<<<dim3(67, 16), 256, 0, stream>>>(scores, boxes, sortedS, sortedB);

    nms3<<<dim3(16), 64, 0, stream>>>(sortedS, sortedB, out);
}

// Round 14
// 4999.293 us; speedup vs baseline: 1.3254x; 1.3254x over previous
//
#include <hip/hip_runtime.h>
#include <math.h>

#define NB 16
#define NC 512
#define NH 38
#define NW 50
#define NHW 1900          // 38*50
#define NPOS 30400        // 16*1900
#define NANCH 17100       // 1900*9
#define PRE_N 6000
#define POST_N 300
#define KTOT 4608         // 512*9
#define NIT 576           // KTOT/8
#define IMGH 608.0f
#define IMGW 800.0f

// ---------------------------------------------------------------------------
// Kernel 1: 3x3 conv (pad 1) + bias + ReLU, implicit GEMM, f64 VALU.
// v7 = v6 with the epilogue position mapping FIXED: with the straight B
// layout, bv[n]=Bd[kk][n*16+tx] holds position n*16+tx, so the store must
// scatter acc[m][n] to pos0 + n*16 + tx (v6 kept v4's tx*4+n -> permuted
// tile -> r13's 784 failure).
//   - __launch_bounds__(256,4): cap VGPR -> 4 waves/SIMD (latency hiding).
//   - straight Bd[kk][pi]: conflict-free ds writes AND reads.
// Per-output-element k-order serial 0..4607, identical fused-FMA expressions
// -> bitwise identical to the verified r4..r11 activations.
// Grid (30 pos-tiles, 4 co-tiles, 16 b), block 256.
// ---------------------------------------------------------------------------
__global__ __launch_bounds__(256, 4)
void conv_f64_v7(const float* __restrict__ x, const float* __restrict__ w,
                 const float* __restrict__ bias, float* __restrict__ out)
{
    const int b    = blockIdx.z;
    const int co0  = blockIdx.y * 128;
    const int pos0 = blockIdx.x * 64;

    __shared__ __align__(16) double Ad[2][8][130];   // [buf][k][co]
    __shared__ __align__(16) double Bd[2][8][64];    // [buf][k][pos]  (straight)

    const int tid = threadIdx.x;
    const int ty  = tid >> 4;    // 0..15: co group (8 consecutive co)
    const int tx  = tid & 15;    // 0..15: pos sub-index

    double acc[8][4];
#pragma unroll
    for (int m = 0; m < 8; ++m)
#pragma unroll
        for (int n = 0; n < 4; ++n) acc[m][n] = 0.0;

    const float* xb = x + (size_t)b * NC * NHW;

    // ---- A staging: thread -> (coiA = tid>>1, k4A = (tid&1)*4), one float4
    const int coiA = tid >> 1;
    const int k4A  = (tid & 1) * 4;
    const float* wptr = w + (size_t)(co0 + coiA) * KTOT + k4A;   // +8/iter

    // ---- B staging: thread owns fixed kkB = tid>>5 (0..7), positions
    //      piB = tid&31 and piB+32 (straight layout).
    const int kkB  = tid >> 5;
    const int piB  = tid & 31;
    const int pB1  = pos0 + piB;
    const int pB2  = pos0 + piB + 32;
    const int py1  = pB1 / NW, px1 = pB1 - (pB1 / NW) * NW;
    const int py2  = pB2 / NW, px2 = pB2 - (pB2 / NW) * NW;
    const bool ok1 = pB1 < NHW;
    const bool ok2 = pB2 < NHW;

    // incremental im2col state for this thread's k = it*8 + kkB
    int ci = 0;
    int ky = kkB / 3;
    int kx = kkB - 3 * (kkB / 3);
    const float* xci = xb;

    // ---- prologue: load + stage tile 0 into buf 0 ----
    float4 wa = *reinterpret_cast<const float4*>(wptr);
    float bs0, bs1;
    {
        const int yy1 = py1 + ky - 1, xx1 = px1 + kx - 1;
        const int yy2 = py2 + ky - 1, xx2 = px2 + kx - 1;
        bs0 = (ok1 && (unsigned)yy1 < (unsigned)NH && (unsigned)xx1 < (unsigned)NW)
                  ? xci[yy1 * NW + xx1] : 0.f;
        bs1 = (ok2 && (unsigned)yy2 < (unsigned)NH && (unsigned)xx2 < (unsigned)NW)
                  ? xci[yy2 * NW + xx2] : 0.f;
    }
    {   // advance state: k += 8  <=>  rr -= 1 (mod 9) with ci carry
        const bool wrap = (ky == 0) && (kx == 0);
        if (wrap) { ky = 2; kx = 2; }
        else {
            --kx;
            if (kx < 0) { kx = 2; --ky; }
            ++ci; xci += NHW;
        }
    }
    Ad[0][k4A + 0][coiA] = (double)wa.x;
    Ad[0][k4A + 1][coiA] = (double)wa.y;
    Ad[0][k4A + 2][coiA] = (double)wa.z;
    Ad[0][k4A + 3][coiA] = (double)wa.w;
    Bd[0][kkB][piB]      = (double)bs0;
    Bd[0][kkB][piB + 32] = (double)bs1;
    __syncthreads();

    int cur = 0;
    for (int it = 0; it < NIT; ++it) {
        const bool more = (it + 1) < NIT;
        // ---- issue global loads for tile it+1 (overlap with FMA below) ----
        if (more) {
            wptr += 8;
            wa = *reinterpret_cast<const float4*>(wptr);
            const int yy1 = py1 + ky - 1, xx1 = px1 + kx - 1;
            const int yy2 = py2 + ky - 1, xx2 = px2 + kx - 1;
            bs0 = (ok1 && (unsigned)yy1 < (unsigned)NH && (unsigned)xx1 < (unsigned)NW)
                      ? xci[yy1 * NW + xx1] : 0.f;
            bs1 = (ok2 && (unsigned)yy2 < (unsigned)NH && (unsigned)xx2 < (unsigned)NW)
                      ? xci[yy2 * NW + xx2] : 0.f;
            const bool wrap = (ky == 0) && (kx == 0);
            if (wrap) { ky = 2; kx = 2; }
            else {
                --kx;
                if (kx < 0) { kx = 2; --ky; }
                ++ci; xci += NHW;
            }
        }

        // ---- FMA block on buf[cur]: bv[n] holds position n*16+tx ----
#pragma unroll
        for (int kk = 0; kk < 8; ++kk) {
            double av[8], bv[4];
#pragma unroll
            for (int m = 0; m < 8; ++m) av[m] = Ad[cur][kk][ty * 8 + m];
#pragma unroll
            for (int n = 0; n < 4; ++n) bv[n] = Bd[cur][kk][n * 16 + tx];
#pragma unroll
            for (int m = 0; m < 8; ++m)
#pragma unroll
                for (int n = 0; n < 4; ++n) acc[m][n] += av[m] * bv[n];
        }

        // ---- stage tile it+1 into the other buffer ----
        if (more) {
            const int nb = cur ^ 1;
            Ad[nb][k4A + 0][coiA] = (double)wa.x;
            Ad[nb][k4A + 1][coiA] = (double)wa.y;
            Ad[nb][k4A + 2][coiA] = (double)wa.z;
            Ad[nb][k4A + 3][coiA] = (double)wa.w;
            Bd[nb][kkB][piB]      = (double)bs0;
            Bd[nb][kkB][piB + 32] = (double)bs1;
            __syncthreads();
        }
        cur ^= 1;
    }

    // ---- epilogue (FIXED): acc[m][n] -> pos = pos0 + n*16 + tx ----
#pragma unroll
    for (int m = 0; m < 8; ++m) {
        const int co = co0 + ty * 8 + m;
        const double bi = (double)bias[co];
        float* orow = out + ((size_t)b * NC + co) * NHW;
#pragma unroll
        for (int n = 0; n < 4; ++n) {
            const int pos = pos0 + n * 16 + tx;
            if (pos < NHW) {
                const double d = acc[m][n] + bi;
                orow[pos] = (float)(d > 0.0 ? d : 0.0);
            }
        }
    }
}

// ---------------------------------------------------------------------------
// Kernel 2: head (18 cls + 36 reg 1x1) with FP64 accumulation (verified r4,
// byte-identical).
// ---------------------------------------------------------------------------
__global__ __launch_bounds__(256)
void head_f64(const float* __restrict__ act,
              const float* __restrict__ cls_w, const float* __restrict__ cls_b,
              const float* __restrict__ reg_w, const float* __restrict__ reg_b,
              float* __restrict__ boxes, float* __restrict__ scores)
{
    const int p = blockIdx.x * 256 + threadIdx.x;
    if (p >= NPOS) return;
    const int b  = p / NHW;
    const int hw = p - b * NHW;

    const float* av = act + (size_t)b * NC * NHW + hw;

    double acc[54];
#pragma unroll
    for (int o = 0; o < 54; ++o) acc[o] = 0.0;

    for (int c = 0; c < NC; ++c) {
        const double v = (double)av[(size_t)c * NHW];
#pragma unroll
        for (int o = 0; o < 18; ++o) acc[o]      += v * (double)cls_w[o * NC + c];
#pragma unroll
        for (int o = 0; o < 36; ++o) acc[18 + o] += v * (double)reg_w[o * NC + c];
    }

    float lg[18];
#pragma unroll
    for (int o = 0; o < 18; ++o) lg[o] = (float)(acc[o] + (double)cls_b[o]);
    float loc[36];
#pragma unroll
    for (int o = 0; o < 36; ++o) loc[o] = (float)(acc[18 + o] + (double)reg_b[o]);

    double mx = -1e300;
#pragma unroll
    for (int o = 0; o < 18; ++o) mx = fmax(mx, (double)lg[o]);
    double sum = 0.0;
#pragma unroll
    for (int o = 0; o < 18; ++o) sum += exp((double)lg[o] - mx);
    const double inv = 1.0 / sum;

    const int hy = hw / NW;
    const int hx = hw - hy * NW;
    const float shy = (float)(hy * 16);
    const float shx = (float)(hx * 16);

    const double rats[3] = {0.5, 1.0, 2.0};
    const double scls[3] = {8.0, 16.0, 32.0};

#pragma unroll
    for (int a = 0; a < 9; ++a) {
        const int ir = a / 3, is = a - ir * 3;
        const double hh = 16.0 * scls[is] * sqrt(rats[ir]);
        const double wd = 16.0 * scls[is] * sqrt(1.0 / rats[ir]);
        const float ay1 = (float)(8.0 - hh * 0.5) + shy;
        const float ax1 = (float)(8.0 - wd * 0.5) + shx;
        const float ay2 = (float)(8.0 + hh * 0.5) + shy;
        const float ax2 = (float)(8.0 + wd * 0.5) + shx;
        const float ahf = ay2 - ay1;
        const float awf = ax2 - ax1;
        const float acy = ay1 + 0.5f * ahf;
        const float acx = ax1 + 0.5f * awf;

        const double ah = (double)ahf, aw = (double)awf;
        const double dy = (double)loc[4 * a + 0];
        const double dx = (double)loc[4 * a + 1];
        const double dh = (double)loc[4 * a + 2];
        const double dw = (double)loc[4 * a + 3];
        const double cy = dy * ah + (double)acy;
        const double cx = dx * aw + (double)acx;
        const double bh = exp(dh) * ah;
        const double bw = exp(dw) * aw;
        float y1 = (float)(cy - 0.5 * bh);
        float x1 = (float)(cx - 0.5 * bw);
        float y2 = (float)(cy + 0.5 * bh);
        float x2 = (float)(cx + 0.5 * bw);
        y1 = fminf(fmaxf(y1, 0.f), IMGH);
        y2 = fminf(fmaxf(y2, 0.f), IMGH);
        x1 = fminf(fmaxf(x1, 0.f), IMGW);
        x2 = fminf(fmaxf(x2, 0.f), IMGW);
        const bool keep = ((y2 - y1) >= 16.0f) && ((x2 - x1) >= 16.0f);

        float sc = (float)(exp((double)lg[2 * a + 1] - mx) * inv);
        if (!keep) sc = -INFINITY;

        const int n = hw * 9 + a;
        float4 bx; bx.x = y1; bx.y = x1; bx.z = y2; bx.w = x2;
        *reinterpret_cast<float4*>(&boxes[((size_t)b * NANCH + n) * 4]) = bx;
        scores[(size_t)b * NANCH + n] = sc;
    }
}

// ---------------------------------------------------------------------------
// Kernel 3: exact rank sort (verified r4, byte-identical).
// ---------------------------------------------------------------------------
__global__ __launch_bounds__(256)
void rank2(const float* __restrict__ scores, const float* __restrict__ boxes,
           float* __restrict__ sortedS, float* __restrict__ sortedB)
{
    const int b = blockIdx.y;
    const int i = blockIdx.x * 256 + threadIdx.x;
    if (i >= NANCH) return;
    const float si = scores[(size_t)b * NANCH + i];
    const float* sb = scores + (size_t)b * NANCH;
    int rank = 0;
    for (int j = 0; j < NANCH; ++j) {
        const float sj = sb[j];
        rank += (sj > si) || (sj == si && j < i);
    }
    if (rank < PRE_N) {
        sortedS[(size_t)b * PRE_N + rank] = si;
        const float4 bx = *reinterpret_cast<const float4*>(&boxes[((size_t)b * NANCH + i) * 4]);
        *reinterpret_cast<float4*>(&sortedB[((size_t)b * PRE_N + rank) * 4]) = bx;
    }
}

// ---------------------------------------------------------------------------
// Kernel 4: greedy NMS, kept-list formulation. PROVEN bitwise-identical to
// the reference-literal nms2 on this workload (r7+r8 shadow probes).
// ---------------------------------------------------------------------------
__global__ __launch_bounds__(64)
void nms3(const float* __restrict__ sortedS, const float* __restrict__ sortedB,
          float* __restrict__ out)
{
    const int b    = blockIdx.x;
    const int lane = threadIdx.x;

    __shared__ float ky1[POST_N], kx1[POST_N], ky2[POST_N], kx2[POST_N];
    __shared__ float kar[POST_N], ksc[POST_N];
    __shared__ float cs[256];
    __shared__ float cb[256][4];

    const float* SS = sortedS + (size_t)b * PRE_N;
    const float* BB = sortedB + (size_t)b * PRE_N * 4;

    int nk = 0;
    bool done = false;
    for (int c0 = 0; c0 < PRE_N && !done; c0 += 256) {
        __syncthreads();
        for (int i = lane; i < 256; i += 64) {
            const int gi = c0 + i;
            if (gi < PRE_N) {
                cs[i] = SS[gi];
                const float4 bx = *reinterpret_cast<const float4*>(&BB[(size_t)gi * 4]);
                cb[i][0] = bx.x; cb[i][1] = bx.y; cb[i][2] = bx.z; cb[i][3] = bx.w;
            } else {
                cs[i] = -INFINITY;
                cb[i][0] = 0.f; cb[i][1] = 0.f; cb[i][2] = 0.f; cb[i][3] = 0.f;
            }
        }
        __syncthreads();

        for (int ic = 0; ic < 256; ++ic) {
            const float sc = cs[ic];
            if (sc == -INFINITY) { done = true; break; }
            const float y1 = cb[ic][0], x1 = cb[ic][1];
            const float y2 = cb[ic][2], x2 = cb[ic][3];
            const float areaC = fmaxf(y2 - y1, 0.f) * fmaxf(x2 - x1, 0.f);
            bool sup = false;
            for (int t = lane; t < nk; t += 64) {
                const float yy1 = fmaxf(y1, ky1[t]);
                const float xx1 = fmaxf(x1, kx1[t]);
                const float yy2 = fminf(y2, ky2[t]);
                const float xx2 = fminf(x2, kx2[t]);
                const float inter = fmaxf(yy2 - yy1, 0.f) * fmaxf(xx2 - xx1, 0.f);
                const float iou = inter / (areaC + kar[t] - inter + 1e-9f);
                if (iou > 0.7f) sup = true;
            }
            if (__ballot(sup) == 0ull) {
                if (lane == 0) {
                    ky1[nk] = y1; kx1[nk] = x1; ky2[nk] = y2; kx2[nk] = x2;
                    kar[nk] = areaC; ksc[nk] = sc;
                }
                __syncthreads();
                ++nk;
                if (nk == POST_N) { done = true; break; }
            }
        }
    }

    __syncthreads();
    for (int k2 = lane; k2 < POST_N; k2 += 64) {
        float o0 = 0.f, o1 = 0.f, o2 = 0.f, o3 = 0.f, o4 = 0.f;
        if (k2 < nk) {
            o0 = ky1[k2]; o1 = kx1[k2]; o2 = ky2[k2]; o3 = kx2[k2]; o4 = ksc[k2];
        }
        float* orow = out + ((size_t)b * POST_N + k2) * 5;
        orow[0] = o0; orow[1] = o1; orow[2] = o2; orow[3] = o3; orow[4] = o4;
    }
}

// ---------------------------------------------------------------------------
static const float* pick_input(void* const* d_in, const int* in_sizes, int n_in,
                               int want, int fallback)
{
    for (int i = 0; i < n_in; ++i)
        if (in_sizes[i] == want) return (const float*)d_in[i];
    return (const float*)d_in[fallback];
}

extern "C" void kernel_launch(void* const* d_in, const int* in_sizes, int n_in,
                              void* d_out, int out_size, void* d_ws, size_t ws_size,
                              hipStream_t stream)
{
    const float* x       = pick_input(d_in, in_sizes, n_in, 15564800, 0);
    const float* share_w = pick_input(d_in, in_sizes, n_in, 2359296, 1);
    const float* share_b = pick_input(d_in, in_sizes, n_in, 512, 2);
    const float* cls_w   = pick_input(d_in, in_sizes, n_in, 9216, 3);
    const float* cls_b   = pick_input(d_in, in_sizes, n_in, 18, 4);
    const float* reg_w   = pick_input(d_in, in_sizes, n_in, 18432, 5);
    const float* reg_b   = pick_input(d_in, in_sizes, n_in, 36, 6);
    float* out = (float*)d_out;

    // workspace layout (floats); total 17,412,800 = 69.7 MB (fits, r3-r13)
    float* W = (float*)d_ws;
    float* act     = W;                   // 16*512*1900 = 15,564,800
    float* boxes   = W + 15564800;        // 16*17100*4 =  1,094,400
    float* scores  = W + 16659200;        // 16*17100   =    273,600
    float* sortedB = W + 16932800;        // 16*6000*4  =    384,000
    float* sortedS = W + 17316800;        // 16*6000    =     96,000

    conv_f64_v7<<<dim3(30, 4, NB), 256, 0, stream>>>(x, share_w, share_b, act);

    head_f64<<<dim3(119), 256, 0, stream>>>(act, cls_w, cls_b, reg_w, reg_b,
                                            boxes, scores);

    rank2<<<dim3(67, 16), 256, 0, stream>>>(scores, boxes, sortedS, sortedB);

    nms3<<<dim3(16), 64, 0, stream>>>(sortedS, sortedB, out);
}

// Round 15
// 4999.248 us; speedup vs baseline: 1.3255x; 1.0000x over previous
//
#include <hip/hip_runtime.h>
#include <math.h>

#define NB 16
#define NC 512
#define NH 38
#define NW 50
#define NHW 1900          // 38*50
#define NPOS 30400        // 16*1900
#define NANCH 17100       // 1900*9
#define PRE_N 6000
#define POST_N 300
#define KTOT 4608         // 512*9
#define NIT 576           // KTOT/8
#define IMGH 608.0f
#define IMGW 800.0f

// ---------------------------------------------------------------------------
// Kernel 1: 3x3 conv (pad 1) + bias + ReLU, implicit GEMM, f64 VALU.
// v7 (verified r14, absmax 0): 128co x 64pos, BK=8, 8x4 f64 acc, straight B
// LDS layout (conflict-free), double-buffered, launch_bounds(256,4).
// Per-output-element k-order serial 0..4607 -> bitwise identical activations.
// Grid (30 pos-tiles, 4 co-tiles, 16 b), block 256.  UNCHANGED.
// ---------------------------------------------------------------------------
__global__ __launch_bounds__(256, 4)
void conv_f64_v7(const float* __restrict__ x, const float* __restrict__ w,
                 const float* __restrict__ bias, float* __restrict__ out)
{
    const int b    = blockIdx.z;
    const int co0  = blockIdx.y * 128;
    const int pos0 = blockIdx.x * 64;

    __shared__ __align__(16) double Ad[2][8][130];   // [buf][k][co]
    __shared__ __align__(16) double Bd[2][8][64];    // [buf][k][pos]  (straight)

    const int tid = threadIdx.x;
    const int ty  = tid >> 4;    // 0..15: co group (8 consecutive co)
    const int tx  = tid & 15;    // 0..15: pos sub-index

    double acc[8][4];
#pragma unroll
    for (int m = 0; m < 8; ++m)
#pragma unroll
        for (int n = 0; n < 4; ++n) acc[m][n] = 0.0;

    const float* xb = x + (size_t)b * NC * NHW;

    const int coiA = tid >> 1;
    const int k4A  = (tid & 1) * 4;
    const float* wptr = w + (size_t)(co0 + coiA) * KTOT + k4A;   // +8/iter

    const int kkB  = tid >> 5;
    const int piB  = tid & 31;
    const int pB1  = pos0 + piB;
    const int pB2  = pos0 + piB + 32;
    const int py1  = pB1 / NW, px1 = pB1 - (pB1 / NW) * NW;
    const int py2  = pB2 / NW, px2 = pB2 - (pB2 / NW) * NW;
    const bool ok1 = pB1 < NHW;
    const bool ok2 = pB2 < NHW;

    int ci = 0;
    int ky = kkB / 3;
    int kx = kkB - 3 * (kkB / 3);
    const float* xci = xb;

    float4 wa = *reinterpret_cast<const float4*>(wptr);
    float bs0, bs1;
    {
        const int yy1 = py1 + ky - 1, xx1 = px1 + kx - 1;
        const int yy2 = py2 + ky - 1, xx2 = px2 + kx - 1;
        bs0 = (ok1 && (unsigned)yy1 < (unsigned)NH && (unsigned)xx1 < (unsigned)NW)
                  ? xci[yy1 * NW + xx1] : 0.f;
        bs1 = (ok2 && (unsigned)yy2 < (unsigned)NH && (unsigned)xx2 < (unsigned)NW)
                  ? xci[yy2 * NW + xx2] : 0.f;
    }
    {
        const bool wrap = (ky == 0) && (kx == 0);
        if (wrap) { ky = 2; kx = 2; }
        else {
            --kx;
            if (kx < 0) { kx = 2; --ky; }
            ++ci; xci += NHW;
        }
    }
    Ad[0][k4A + 0][coiA] = (double)wa.x;
    Ad[0][k4A + 1][coiA] = (double)wa.y;
    Ad[0][k4A + 2][coiA] = (double)wa.z;
    Ad[0][k4A + 3][coiA] = (double)wa.w;
    Bd[0][kkB][piB]      = (double)bs0;
    Bd[0][kkB][piB + 32] = (double)bs1;
    __syncthreads();

    int cur = 0;
    for (int it = 0; it < NIT; ++it) {
        const bool more = (it + 1) < NIT;
        if (more) {
            wptr += 8;
            wa = *reinterpret_cast<const float4*>(wptr);
            const int yy1 = py1 + ky - 1, xx1 = px1 + kx - 1;
            const int yy2 = py2 + ky - 1, xx2 = px2 + kx - 1;
            bs0 = (ok1 && (unsigned)yy1 < (unsigned)NH && (unsigned)xx1 < (unsigned)NW)
                      ? xci[yy1 * NW + xx1] : 0.f;
            bs1 = (ok2 && (unsigned)yy2 < (unsigned)NH && (unsigned)xx2 < (unsigned)NW)
                      ? xci[yy2 * NW + xx2] : 0.f;
            const bool wrap = (ky == 0) && (kx == 0);
            if (wrap) { ky = 2; kx = 2; }
            else {
                --kx;
                if (kx < 0) { kx = 2; --ky; }
                ++ci; xci += NHW;
            }
        }

#pragma unroll
        for (int kk = 0; kk < 8; ++kk) {
            double av[8], bv[4];
#pragma unroll
            for (int m = 0; m < 8; ++m) av[m] = Ad[cur][kk][ty * 8 + m];
#pragma unroll
            for (int n = 0; n < 4; ++n) bv[n] = Bd[cur][kk][n * 16 + tx];
#pragma unroll
            for (int m = 0; m < 8; ++m)
#pragma unroll
                for (int n = 0; n < 4; ++n) acc[m][n] += av[m] * bv[n];
        }

        if (more) {
            const int nb = cur ^ 1;
            Ad[nb][k4A + 0][coiA] = (double)wa.x;
            Ad[nb][k4A + 1][coiA] = (double)wa.y;
            Ad[nb][k4A + 2][coiA] = (double)wa.z;
            Ad[nb][k4A + 3][coiA] = (double)wa.w;
            Bd[nb][kkB][piB]      = (double)bs0;
            Bd[nb][kkB][piB + 32] = (double)bs1;
            __syncthreads();
        }
        cur ^= 1;
    }

    // epilogue: acc[m][n] -> pos = pos0 + n*16 + tx
#pragma unroll
    for (int m = 0; m < 8; ++m) {
        const int co = co0 + ty * 8 + m;
        const double bi = (double)bias[co];
        float* orow = out + ((size_t)b * NC + co) * NHW;
#pragma unroll
        for (int n = 0; n < 4; ++n) {
            const int pos = pos0 + n * 16 + tx;
            if (pos < NHW) {
                const double d = acc[m][n] + bi;
                orow[pos] = (float)(d > 0.0 ? d : 0.0);
            }
        }
    }
}

// ---------------------------------------------------------------------------
// Kernel 2a: head partial — 6-way output split for parallelism (119 blocks
// was <0.5 wave/SIMD). Block g computes outputs g*9..g*9+8 for 256 positions.
// Per-output c-order serial 0..511, identical expressions to the verified
// head_f64 -> hl[b][o][hw] f32 values are bitwise identical to the r4 logits
// and locs (= the reference's cls/reg tensors).
// Grid (119, 6), block 256.
// ---------------------------------------------------------------------------
__global__ __launch_bounds__(256)
void head_part(const float* __restrict__ act,
               const float* __restrict__ cls_w, const float* __restrict__ cls_b,
               const float* __restrict__ reg_w, const float* __restrict__ reg_b,
               float* __restrict__ hl)
{
    const int p = blockIdx.x * 256 + threadIdx.x;
    if (p >= NPOS) return;
    const int g  = blockIdx.y;          // 0..5, uniform per block
    const int b  = p / NHW;
    const int hw = p - b * NHW;

    const float* av = act + (size_t)b * NC * NHW + hw;

    const float* wrow[9];
    double bia[9];
#pragma unroll
    for (int j = 0; j < 9; ++j) {
        const int o = g * 9 + j;
        if (o < 18) { wrow[j] = cls_w + (size_t)o * NC;        bia[j] = (double)cls_b[o]; }
        else        { wrow[j] = reg_w + (size_t)(o - 18) * NC; bia[j] = (double)reg_b[o - 18]; }
    }

    double acc[9];
#pragma unroll
    for (int j = 0; j < 9; ++j) acc[j] = 0.0;

    for (int c = 0; c < NC; ++c) {
        const double v = (double)av[(size_t)c * NHW];
#pragma unroll
        for (int j = 0; j < 9; ++j) acc[j] += v * (double)wrow[j][c];
    }

    float* hb = hl + (size_t)b * 54 * NHW + hw;
#pragma unroll
    for (int j = 0; j < 9; ++j)
        hb[(size_t)(g * 9 + j) * NHW] = (float)(acc[j] + bia[j]);
}

// ---------------------------------------------------------------------------
// Kernel 2b: decode — reads the 54 f32 logits/locs, softmax in f64, anchor
// decode + clip + min-size (identical expressions to the verified head_f64
// downstream -> bitwise identical boxes/scores).
// ---------------------------------------------------------------------------
__global__ __launch_bounds__(256)
void decode_k(const float* __restrict__ hl,
              float* __restrict__ boxes, float* __restrict__ scores)
{
    const int p = blockIdx.x * 256 + threadIdx.x;
    if (p >= NPOS) return;
    const int b  = p / NHW;
    const int hw = p - b * NHW;

    const float* hb = hl + (size_t)b * 54 * NHW + hw;

    float lg[18];
#pragma unroll
    for (int o = 0; o < 18; ++o) lg[o] = hb[(size_t)o * NHW];
    float loc[36];
#pragma unroll
    for (int o = 0; o < 36; ++o) loc[o] = hb[(size_t)(18 + o) * NHW];

    double mx = -1e300;
#pragma unroll
    for (int o = 0; o < 18; ++o) mx = fmax(mx, (double)lg[o]);
    double sum = 0.0;
#pragma unroll
    for (int o = 0; o < 18; ++o) sum += exp((double)lg[o] - mx);
    const double inv = 1.0 / sum;

    const int hy = hw / NW;
    const int hx = hw - hy * NW;
    const float shy = (float)(hy * 16);
    const float shx = (float)(hx * 16);

    const double rats[3] = {0.5, 1.0, 2.0};
    const double scls[3] = {8.0, 16.0, 32.0};

#pragma unroll
    for (int a = 0; a < 9; ++a) {
        const int ir = a / 3, is = a - ir * 3;
        const double hh = 16.0 * scls[is] * sqrt(rats[ir]);
        const double wd = 16.0 * scls[is] * sqrt(1.0 / rats[ir]);
        const float ay1 = (float)(8.0 - hh * 0.5) + shy;
        const float ax1 = (float)(8.0 - wd * 0.5) + shx;
        const float ay2 = (float)(8.0 + hh * 0.5) + shy;
        const float ax2 = (float)(8.0 + wd * 0.5) + shx;
        const float ahf = ay2 - ay1;
        const float awf = ax2 - ax1;
        const float acy = ay1 + 0.5f * ahf;
        const float acx = ax1 + 0.5f * awf;

        const double ah = (double)ahf, aw = (double)awf;
        const double dy = (double)loc[4 * a + 0];
        const double dx = (double)loc[4 * a + 1];
        const double dh = (double)loc[4 * a + 2];
        const double dw = (double)loc[4 * a + 3];
        const double cy = dy * ah + (double)acy;
        const double cx = dx * aw + (double)acx;
        const double bh = exp(dh) * ah;
        const double bw = exp(dw) * aw;
        float y1 = (float)(cy - 0.5 * bh);
        float x1 = (float)(cx - 0.5 * bw);
        float y2 = (float)(cy + 0.5 * bh);
        float x2 = (float)(cx + 0.5 * bw);
        y1 = fminf(fmaxf(y1, 0.f), IMGH);
        y2 = fminf(fmaxf(y2, 0.f), IMGH);
        x1 = fminf(fmaxf(x1, 0.f), IMGW);
        x2 = fminf(fmaxf(x2, 0.f), IMGW);
        const bool keep = ((y2 - y1) >= 16.0f) && ((x2 - x1) >= 16.0f);

        float sc = (float)(exp((double)lg[2 * a + 1] - mx) * inv);
        if (!keep) sc = -INFINITY;

        const int n = hw * 9 + a;
        float4 bx; bx.x = y1; bx.y = x1; bx.z = y2; bx.w = x2;
        *reinterpret_cast<float4*>(&boxes[((size_t)b * NANCH + n) * 4]) = bx;
        scores[(size_t)b * NANCH + n] = sc;
    }
}

// ---------------------------------------------------------------------------
// Kernel 3: exact rank sort (verified r4, byte-identical).
// ---------------------------------------------------------------------------
__global__ __launch_bounds__(256)
void rank2(const float* __restrict__ scores, const float* __restrict__ boxes,
           float* __restrict__ sortedS, float* __restrict__ sortedB)
{
    const int b = blockIdx.y;
    const int i = blockIdx.x * 256 + threadIdx.x;
    if (i >= NANCH) return;
    const float si = scores[(size_t)b * NANCH + i];
    const float* sb = scores + (size_t)b * NANCH;
    int rank = 0;
    for (int j = 0; j < NANCH; ++j) {
        const float sj = sb[j];
        rank += (sj > si) || (sj == si && j < i);
    }
    if (rank < PRE_N) {
        sortedS[(size_t)b * PRE_N + rank] = si;
        const float4 bx = *reinterpret_cast<const float4*>(&boxes[((size_t)b * NANCH + i) * 4]);
        *reinterpret_cast<float4*>(&sortedB[((size_t)b * PRE_N + rank) * 4]) = bx;
    }
}

// ---------------------------------------------------------------------------
// Kernel 4: greedy NMS, kept-list formulation. PROVEN bitwise-identical to
// the reference-literal nms2 on this workload (r7+r8 shadow probes).
// ---------------------------------------------------------------------------
__global__ __launch_bounds__(64)
void nms3(const float* __restrict__ sortedS, const float* __restrict__ sortedB,
          float* __restrict__ out)
{
    const int b    = blockIdx.x;
    const int lane = threadIdx.x;

    __shared__ float ky1[POST_N], kx1[POST_N], ky2[POST_N], kx2[POST_N];
    __shared__ float kar[POST_N], ksc[POST_N];
    __shared__ float cs[256];
    __shared__ float cb[256][4];

    const float* SS = sortedS + (size_t)b * PRE_N;
    const float* BB = sortedB + (size_t)b * PRE_N * 4;

    int nk = 0;
    bool done = false;
    for (int c0 = 0; c0 < PRE_N && !done; c0 += 256) {
        __syncthreads();
        for (int i = lane; i < 256; i += 64) {
            const int gi = c0 + i;
            if (gi < PRE_N) {
                cs[i] = SS[gi];
                const float4 bx = *reinterpret_cast<const float4*>(&BB[(size_t)gi * 4]);
                cb[i][0] = bx.x; cb[i][1] = bx.y; cb[i][2] = bx.z; cb[i][3] = bx.w;
            } else {
                cs[i] = -INFINITY;
                cb[i][0] = 0.f; cb[i][1] = 0.f; cb[i][2] = 0.f; cb[i][3] = 0.f;
            }
        }
        __syncthreads();

        for (int ic = 0; ic < 256; ++ic) {
            const float sc = cs[ic];
            if (sc == -INFINITY) { done = true; break; }
            const float y1 = cb[ic][0], x1 = cb[ic][1];
            const float y2 = cb[ic][2], x2 = cb[ic][3];
            const float areaC = fmaxf(y2 - y1, 0.f) * fmaxf(x2 - x1, 0.f);
            bool sup = false;
            for (int t = lane; t < nk; t += 64) {
                const float yy1 = fmaxf(y1, ky1[t]);
                const float xx1 = fmaxf(x1, kx1[t]);
                const float yy2 = fminf(y2, ky2[t]);
                const float xx2 = fminf(x2, kx2[t]);
                const float inter = fmaxf(yy2 - yy1, 0.f) * fmaxf(xx2 - xx1, 0.f);
                const float iou = inter / (areaC + kar[t] - inter + 1e-9f);
                if (iou > 0.7f) sup = true;
            }
            if (__ballot(sup) == 0ull) {
                if (lane == 0) {
                    ky1[nk] = y1; kx1[nk] = x1; ky2[nk] = y2; kx2[nk] = x2;
                    kar[nk] = areaC; ksc[nk] = sc;
                }
                __syncthreads();
                ++nk;
                if (nk == POST_N) { done = true; break; }
            }
        }
    }

    __syncthreads();
    for (int k2 = lane; k2 < POST_N; k2 += 64) {
        float o0 = 0.f, o1 = 0.f, o2 = 0.f, o3 = 0.f, o4 = 0.f;
        if (k2 < nk) {
            o0 = ky1[k2]; o1 = kx1[k2]; o2 = ky2[k2]; o3 = kx2[k2]; o4 = ksc[k2];
        }
        float* orow = out + ((size_t)b * POST_N + k2) * 5;
        orow[0] = o0; orow[1] = o1; orow[2] = o2; orow[3] = o3; orow[4] = o4;
    }
}

// ---------------------------------------------------------------------------
static const float* pick_input(void* const* d_in, const int* in_sizes, int n_in,
                               int want, int fallback)
{
    for (int i = 0; i < n_in; ++i)
        if (in_sizes[i] == want) return (const float*)d_in[i];
    return (const float*)d_in[fallback];
}

extern "C" void kernel_launch(void* const* d_in, const int* in_sizes, int n_in,
                              void* d_out, int out_size, void* d_ws, size_t ws_size,
                              hipStream_t stream)
{
    const float* x       = pick_input(d_in, in_sizes, n_in, 15564800, 0);
    const float* share_w = pick_input(d_in, in_sizes, n_in, 2359296, 1);
    const float* share_b = pick_input(d_in, in_sizes, n_in, 512, 2);
    const float* cls_w   = pick_input(d_in, in_sizes, n_in, 9216, 3);
    const float* cls_b   = pick_input(d_in, in_sizes, n_in, 18, 4);
    const float* reg_w   = pick_input(d_in, in_sizes, n_in, 18432, 5);
    const float* reg_b   = pick_input(d_in, in_sizes, n_in, 36, 6);
    float* out = (float*)d_out;

    // workspace layout (floats); total 19,054,400 = 76.2 MB (132 MB proven, r7)
    float* W = (float*)d_ws;
    float* act     = W;                   // 16*512*1900 = 15,564,800
    float* boxes   = W + 15564800;        // 16*17100*4 =  1,094,400
    float* scores  = W + 16659200;        // 16*17100   =    273,600
    float* sortedB = W + 16932800;        // 16*6000*4  =    384,000
    float* sortedS = W + 17316800;        // 16*6000    =     96,000
    float* hl      = W + 17412800;        // 16*54*1900 =  1,641,600

    conv_f64_v7<<<dim3(30, 4, NB), 256, 0, stream>>>(x, share_w, share_b, act);

    head_part<<<dim3(119, 6), 256, 0, stream>>>(act, cls_w, cls_b,
                                                reg_w, reg_b, hl);

    decode_k<<<dim3(119), 256, 0, stream>>>(hl, boxes, scores);

    rank2<<<dim3(67, 16), 256, 0, stream>>>(scores, boxes, sortedS, sortedB);

    nms3<<<dim3(16), 64, 0, stream>>>(sortedS, sortedB, out);
}

// Round 16
// 4887.653 us; speedup vs baseline: 1.3557x; 1.0228x over previous
//
#include <hip/hip_runtime.h>
#include <math.h>

#define NB 16
#define NC 512
#define NH 38
#define NW 50
#define NHW 1900          // 38*50
#define NPOS 30400        // 16*1900
#define NANCH 17100       // 1900*9
#define PRE_N 6000
#define POST_N 300
#define KTOT 4608         // 512*9
#define NIT 576           // KTOT/8
#define IMGH 608.0f
#define IMGW 800.0f

// ---------------------------------------------------------------------------
// Kernel 1: 3x3 conv (pad 1) + bias + ReLU, implicit GEMM, f64 VALU.
// v8 = v7 structure (straight LDS, double-buffered, 1 barrier/iter,
// incremental im2col, reg-prefetch overlapping the FMA block) with the
// per-thread tile doubled to 8x8 (block 128co x 128pos): LDS-read instrs
// drop from 0.25 to 0.19 per FMA and staging/barrier amortize 2x. ~190 VGPR
// -> 2 waves/SIMD; 64 independent f64 accumulators provide the ILP to keep
// the 4-cy f64 pipe fed.
// Per-output-element k-order serial 0..4607, identical fused-FMA expressions
// -> bitwise identical to the verified r4..r15 activations.
// Grid (15 pos-tiles, 4 co-tiles, 16 b), block 256.
// ---------------------------------------------------------------------------
__global__ __launch_bounds__(256, 2)
void conv_f64_v8(const float* __restrict__ x, const float* __restrict__ w,
                 const float* __restrict__ bias, float* __restrict__ out)
{
    const int b    = blockIdx.z;
    const int co0  = blockIdx.y * 128;
    const int pos0 = blockIdx.x * 128;

    __shared__ __align__(16) double Ad[2][8][130];   // [buf][k][co]
    __shared__ __align__(16) double Bd[2][8][128];   // [buf][k][pos] (straight)

    const int tid = threadIdx.x;
    const int ty  = tid >> 4;    // 0..15: co group (8 consecutive co)
    const int tx  = tid & 15;    // 0..15: pos sub-index

    double acc[8][8];
#pragma unroll
    for (int m = 0; m < 8; ++m)
#pragma unroll
        for (int n = 0; n < 8; ++n) acc[m][n] = 0.0;

    const float* xb = x + (size_t)b * NC * NHW;

    // ---- A staging: thread -> (coiA = tid>>1 in [0,128), k4A), one float4
    const int coiA = tid >> 1;
    const int k4A  = (tid & 1) * 4;
    const float* wptr = w + (size_t)(co0 + coiA) * KTOT + k4A;   // +8/iter

    // ---- B staging: thread owns fixed kkB = tid>>5 (0..7), 4 positions
    //      piB + j*32 (straight layout).
    const int kkB = tid >> 5;
    const int piB = tid & 31;
    int  pyj[4], pxj[4];
    bool okj[4];
#pragma unroll
    for (int j = 0; j < 4; ++j) {
        const int p = pos0 + piB + j * 32;
        const int py = p / NW;
        pyj[j] = py;
        pxj[j] = p - py * NW;
        okj[j] = p < NHW;
    }

    // incremental im2col state for this thread's k = it*8 + kkB
    int ky = kkB / 3;
    int kx = kkB - 3 * (kkB / 3);
    const float* xci = xb;

    float4 wa;
    float  bs[4];

#define LOAD_B()                                                              \
    {                                                                         \
        _Pragma("unroll")                                                     \
        for (int j = 0; j < 4; ++j) {                                         \
            const int yy = pyj[j] + ky - 1;                                   \
            const int xx = pxj[j] + kx - 1;                                   \
            bs[j] = (okj[j] && (unsigned)yy < (unsigned)NH &&                 \
                     (unsigned)xx < (unsigned)NW) ? xci[yy * NW + xx] : 0.f;  \
        }                                                                     \
    }

#define ADV_STATE()                                                           \
    {                                                                         \
        const bool wrap = (ky == 0) && (kx == 0);                             \
        if (wrap) { ky = 2; kx = 2; }                                         \
        else {                                                                \
            --kx;                                                             \
            if (kx < 0) { kx = 2; --ky; }                                     \
            xci += NHW;                                                       \
        }                                                                     \
    }

#define STAGE(buf)                                                            \
    {                                                                         \
        Ad[buf][k4A + 0][coiA] = (double)wa.x;                                \
        Ad[buf][k4A + 1][coiA] = (double)wa.y;                                \
        Ad[buf][k4A + 2][coiA] = (double)wa.z;                                \
        Ad[buf][k4A + 3][coiA] = (double)wa.w;                                \
        _Pragma("unroll")                                                     \
        for (int j = 0; j < 4; ++j) Bd[buf][kkB][piB + j * 32] = (double)bs[j];\
    }

    // ---- prologue: load + stage tile 0 into buf 0 ----
    wa = *reinterpret_cast<const float4*>(wptr);
    LOAD_B();
    ADV_STATE();
    STAGE(0);
    __syncthreads();

    int cur = 0;
    for (int it = 0; it < NIT; ++it) {
        const bool more = (it + 1) < NIT;
        // ---- issue global loads for tile it+1 (overlap with FMA below) ----
        if (more) {
            wptr += 8;
            wa = *reinterpret_cast<const float4*>(wptr);
            LOAD_B();
            ADV_STATE();
        }

        // ---- FMA block on buf[cur]: bv[n] holds position n*16+tx ----
#pragma unroll
        for (int kk = 0; kk < 8; ++kk) {
            double av[8], bv[8];
#pragma unroll
            for (int m = 0; m < 8; ++m) av[m] = Ad[cur][kk][ty * 8 + m];
#pragma unroll
            for (int n = 0; n < 8; ++n) bv[n] = Bd[cur][kk][n * 16 + tx];
#pragma unroll
            for (int m = 0; m < 8; ++m)
#pragma unroll
                for (int n = 0; n < 8; ++n) acc[m][n] += av[m] * bv[n];
        }

        // ---- stage tile it+1 into the other buffer ----
        if (more) {
            const int nb = cur ^ 1;
            STAGE(nb);
            __syncthreads();
        }
        cur ^= 1;
    }
#undef LOAD_B
#undef ADV_STATE
#undef STAGE

    // ---- epilogue: acc[m][n] -> co = co0+ty*8+m, pos = pos0 + n*16 + tx ----
#pragma unroll
    for (int m = 0; m < 8; ++m) {
        const int co = co0 + ty * 8 + m;
        const double bi = (double)bias[co];
        float* orow = out + ((size_t)b * NC + co) * NHW;
#pragma unroll
        for (int n = 0; n < 8; ++n) {
            const int pos = pos0 + n * 16 + tx;
            if (pos < NHW) {
                const double d = acc[m][n] + bi;
                orow[pos] = (float)(d > 0.0 ? d : 0.0);
            }
        }
    }
}

// ---------------------------------------------------------------------------
// Kernel 2a: head partial (verified r15, byte-identical): 6-way output split;
// per-output c-order serial 0..511 -> f32 logits/locs bitwise identical.
// Grid (119, 6), block 256.
// ---------------------------------------------------------------------------
__global__ __launch_bounds__(256)
void head_part(const float* __restrict__ act,
               const float* __restrict__ cls_w, const float* __restrict__ cls_b,
               const float* __restrict__ reg_w, const float* __restrict__ reg_b,
               float* __restrict__ hl)
{
    const int p = blockIdx.x * 256 + threadIdx.x;
    if (p >= NPOS) return;
    const int g  = blockIdx.y;          // 0..5, uniform per block
    const int b  = p / NHW;
    const int hw = p - b * NHW;

    const float* av = act + (size_t)b * NC * NHW + hw;

    const float* wrow[9];
    double bia[9];
#pragma unroll
    for (int j = 0; j < 9; ++j) {
        const int o = g * 9 + j;
        if (o < 18) { wrow[j] = cls_w + (size_t)o * NC;        bia[j] = (double)cls_b[o]; }
        else        { wrow[j] = reg_w + (size_t)(o - 18) * NC; bia[j] = (double)reg_b[o - 18]; }
    }

    double acc[9];
#pragma unroll
    for (int j = 0; j < 9; ++j) acc[j] = 0.0;

    for (int c = 0; c < NC; ++c) {
        const double v = (double)av[(size_t)c * NHW];
#pragma unroll
        for (int j = 0; j < 9; ++j) acc[j] += v * (double)wrow[j][c];
    }

    float* hb = hl + (size_t)b * 54 * NHW + hw;
#pragma unroll
    for (int j = 0; j < 9; ++j)
        hb[(size_t)(g * 9 + j) * NHW] = (float)(acc[j] + bia[j]);
}

// ---------------------------------------------------------------------------
// Kernel 2b: decode (verified r15, byte-identical).
// ---------------------------------------------------------------------------
__global__ __launch_bounds__(256)
void decode_k(const float* __restrict__ hl,
              float* __restrict__ boxes, float* __restrict__ scores)
{
    const int p = blockIdx.x * 256 + threadIdx.x;
    if (p >= NPOS) return;
    const int b  = p / NHW;
    const int hw = p - b * NHW;

    const float* hb = hl + (size_t)b * 54 * NHW + hw;

    float lg[18];
#pragma unroll
    for (int o = 0; o < 18; ++o) lg[o] = hb[(size_t)o * NHW];
    float loc[36];
#pragma unroll
    for (int o = 0; o < 36; ++o) loc[o] = hb[(size_t)(18 + o) * NHW];

    double mx = -1e300;
#pragma unroll
    for (int o = 0; o < 18; ++o) mx = fmax(mx, (double)lg[o]);
    double sum = 0.0;
#pragma unroll
    for (int o = 0; o < 18; ++o) sum += exp((double)lg[o] - mx);
    const double inv = 1.0 / sum;

    const int hy = hw / NW;
    const int hx = hw - hy * NW;
    const float shy = (float)(hy * 16);
    const float shx = (float)(hx * 16);

    const double rats[3] = {0.5, 1.0, 2.0};
    const double scls[3] = {8.0, 16.0, 32.0};

#pragma unroll
    for (int a = 0; a < 9; ++a) {
        const int ir = a / 3, is = a - ir * 3;
        const double hh = 16.0 * scls[is] * sqrt(rats[ir]);
        const double wd = 16.0 * scls[is] * sqrt(1.0 / rats[ir]);
        const float ay1 = (float)(8.0 - hh * 0.5) + shy;
        const float ax1 = (float)(8.0 - wd * 0.5) + shx;
        const float ay2 = (float)(8.0 + hh * 0.5) + shy;
        const float ax2 = (float)(8.0 + wd * 0.5) + shx;
        const float ahf = ay2 - ay1;
        const float awf = ax2 - ax1;
        const float acy = ay1 + 0.5f * ahf;
        const float acx = ax1 + 0.5f * awf;

        const double ah = (double)ahf, aw = (double)awf;
        const double dy = (double)loc[4 * a + 0];
        const double dx = (double)loc[4 * a + 1];
        const double dh = (double)loc[4 * a + 2];
        const double dw = (double)loc[4 * a + 3];
        const double cy = dy * ah + (double)acy;
        const double cx = dx * aw + (double)acx;
        const double bh = exp(dh) * ah;
        const double bw = exp(dw) * aw;
        float y1 = (float)(cy - 0.5 * bh);
        float x1 = (float)(cx - 0.5 * bw);
        float y2 = (float)(cy + 0.5 * bh);
        float x2 = (float)(cx + 0.5 * bw);
        y1 = fminf(fmaxf(y1, 0.f), IMGH);
        y2 = fminf(fmaxf(y2, 0.f), IMGH);
        x1 = fminf(fmaxf(x1, 0.f), IMGW);
        x2 = fminf(fmaxf(x2, 0.f), IMGW);
        const bool keep = ((y2 - y1) >= 16.0f) && ((x2 - x1) >= 16.0f);

        float sc = (float)(exp((double)lg[2 * a + 1] - mx) * inv);
        if (!keep) sc = -INFINITY;

        const int n = hw * 9 + a;
        float4 bx; bx.x = y1; bx.y = x1; bx.z = y2; bx.w = x2;
        *reinterpret_cast<float4*>(&boxes[((size_t)b * NANCH + n) * 4]) = bx;
        scores[(size_t)b * NANCH + n] = sc;
    }
}

// ---------------------------------------------------------------------------
// Kernel 3: exact rank sort (verified r4, byte-identical).
// ---------------------------------------------------------------------------
__global__ __launch_bounds__(256)
void rank2(const float* __restrict__ scores, const float* __restrict__ boxes,
           float* __restrict__ sortedS, float* __restrict__ sortedB)
{
    const int b = blockIdx.y;
    const int i = blockIdx.x * 256 + threadIdx.x;
    if (i >= NANCH) return;
    const float si = scores[(size_t)b * NANCH + i];
    const float* sb = scores + (size_t)b * NANCH;
    int rank = 0;
    for (int j = 0; j < NANCH; ++j) {
        const float sj = sb[j];
        rank += (sj > si) || (sj == si && j < i);
    }
    if (rank < PRE_N) {
        sortedS[(size_t)b * PRE_N + rank] = si;
        const float4 bx = *reinterpret_cast<const float4*>(&boxes[((size_t)b * NANCH + i) * 4]);
        *reinterpret_cast<float4*>(&sortedB[((size_t)b * PRE_N + rank) * 4]) = bx;
    }
}

// ---------------------------------------------------------------------------
// Kernel 4: greedy NMS, kept-list formulation. PROVEN bitwise-identical to
// the reference-literal nms2 on this workload (r7+r8 shadow probes).
// ---------------------------------------------------------------------------
__global__ __launch_bounds__(64)
void nms3(const float* __restrict__ sortedS, const float* __restrict__ sortedB,
          float* __restrict__ out)
{
    const int b    = blockIdx.x;
    const int lane = threadIdx.x;

    __shared__ float ky1[POST_N], kx1[POST_N], ky2[POST_N], kx2[POST_N];
    __shared__ float kar[POST_N], ksc[POST_N];
    __shared__ float cs[256];
    __shared__ float cb[256][4];

    const float* SS = sortedS + (size_t)b * PRE_N;
    const float* BB = sortedB + (size_t)b * PRE_N * 4;

    int nk = 0;
    bool done = false;
    for (int c0 = 0; c0 < PRE_N && !done; c0 += 256) {
        __syncthreads();
        for (int i = lane; i < 256; i += 64) {
            const int gi = c0 + i;
            if (gi < PRE_N) {
                cs[i] = SS[gi];
                const float4 bx = *reinterpret_cast<const float4*>(&BB[(size_t)gi * 4]);
                cb[i][0] = bx.x; cb[i][1] = bx.y; cb[i][2] = bx.z; cb[i][3] = bx.w;
            } else {
                cs[i] = -INFINITY;
                cb[i][0] = 0.f; cb[i][1] = 0.f; cb[i][2] = 0.f; cb[i][3] = 0.f;
            }
        }
        __syncthreads();

        for (int ic = 0; ic < 256; ++ic) {
            const float sc = cs[ic];
            if (sc == -INFINITY) { done = true; break; }
            const float y1 = cb[ic][0], x1 = cb[ic][1];
            const float y2 = cb[ic][2], x2 = cb[ic][3];
            const float areaC = fmaxf(y2 - y1, 0.f) * fmaxf(x2 - x1, 0.f);
            bool sup = false;
            for (int t = lane; t < nk; t += 64) {
                const float yy1 = fmaxf(y1, ky1[t]);
                const float xx1 = fmaxf(x1, kx1[t]);
                const float yy2 = fminf(y2, ky2[t]);
                const float xx2 = fminf(x2, kx2[t]);
                const float inter = fmaxf(yy2 - yy1, 0.f) * fmaxf(xx2 - xx1, 0.f);
                const float iou = inter / (areaC + kar[t] - inter + 1e-9f);
                if (iou > 0.7f) sup = true;
            }
            if (__ballot(sup) == 0ull) {
                if (lane == 0) {
                    ky1[nk] = y1; kx1[nk] = x1; ky2[nk] = y2; kx2[nk] = x2;
                    kar[nk] = areaC; ksc[nk] = sc;
                }
                __syncthreads();
                ++nk;
                if (nk == POST_N) { done = true; break; }
            }
        }
    }

    __syncthreads();
    for (int k2 = lane; k2 < POST_N; k2 += 64) {
        float o0 = 0.f, o1 = 0.f, o2 = 0.f, o3 = 0.f, o4 = 0.f;
        if (k2 < nk) {
            o0 = ky1[k2]; o1 = kx1[k2]; o2 = ky2[k2]; o3 = kx2[k2]; o4 = ksc[k2];
        }
        float* orow = out + ((size_t)b * POST_N + k2) * 5;
        orow[0] = o0; orow[1] = o1; orow[2] = o2; orow[3] = o3; orow[4] = o4;
    }
}

// ---------------------------------------------------------------------------
static const float* pick_input(void* const* d_in, const int* in_sizes, int n_in,
                               int want, int fallback)
{
    for (int i = 0; i < n_in; ++i)
        if (in_sizes[i] == want) return (const float*)d_in[i];
    return (const float*)d_in[fallback];
}

extern "C" void kernel_launch(void* const* d_in, const int* in_sizes, int n_in,
                              void* d_out, int out_size, void* d_ws, size_t ws_size,
                              hipStream_t stream)
{
    const float* x       = pick_input(d_in, in_sizes, n_in, 15564800, 0);
    const float* share_w = pick_input(d_in, in_sizes, n_in, 2359296, 1);
    const float* share_b = pick_input(d_in, in_sizes, n_in, 512, 2);
    const float* cls_w   = pick_input(d_in, in_sizes, n_in, 9216, 3);
    const float* cls_b   = pick_input(d_in, in_sizes, n_in, 18, 4);
    const float* reg_w   = pick_input(d_in, in_sizes, n_in, 18432, 5);
    const float* reg_b   = pick_input(d_in, in_sizes, n_in, 36, 6);
    float* out = (float*)d_out;

    // workspace layout (floats); total 19,054,400 = 76.2 MB (132 MB proven, r7)
    float* W = (float*)d_ws;
    float* act     = W;                   // 16*512*1900 = 15,564,800
    float* boxes   = W + 15564800;        // 16*17100*4 =  1,094,400
    float* scores  = W + 16659200;        // 16*17100   =    273,600
    float* sortedB = W + 16932800;        // 16*6000*4  =    384,000
    float* sortedS = W + 17316800;        // 16*6000    =     96,000
    float* hl      = W + 17412800;        // 16*54*1900 =  1,641,600

    conv_f64_v8<<<dim3(15, 4, NB), 256, 0, stream>>>(x, share_w, share_b, act);

    head_part<<<dim3(119, 6), 256, 0, stream>>>(act, cls_w, cls_b,
                                                reg_w, reg_b, hl);

    decode_k<<<dim3(119), 256, 0, stream>>>(hl, boxes, scores);

    rank2<<<dim3(67, 16), 256, 0, stream>>>(scores, boxes, sortedS, sortedB);

    nms3<<<dim3(16), 64, 0, stream>>>(sortedS, sortedB, out);
}